// Round 5
// baseline (140.533 us; speedup 1.0000x reference)
//
#include <hip/hip_runtime.h>

// SA_Head: B=4, S=4096, E=256, H=64
//   out = softmax((emb@wq)(emb@wk)^T / 16) (emb@wv)
// R5: reduce_kernel regridded 256->1024 blocks (was 1 block/CU, latency-bound).
// attn: Q frags moved to LDS (frees 32 VGPRs), explicit next-tile K/V global
// prefetch, bf16 pack via int-add-round + v_perm (1/3 the VALU of manual RNE).
// Zero-LDS K-loop math otherwise unchanged (S^T form, register-resident P).

typedef short short4v __attribute__((ext_vector_type(4)));
typedef short short8v __attribute__((ext_vector_type(8)));
typedef float floatx4 __attribute__((ext_vector_type(4)));
typedef unsigned short u16;
typedef unsigned int u32;

#define SEQ 4096
#define EMB 256
#define HD 64
#define PADA 264   // u16 stride for proj A tile
#define PADQ 68    // u16 stride for attn q tile

static __device__ __forceinline__ u16 f2bf(float x) {
    union { float f; unsigned u; } v; v.f = x;
    unsigned r = v.u + 0x7FFFu + ((v.u >> 16) & 1u);
    return (u16)(r >> 16);
}

// round-to-nearest (ties away) bf16 pair pack: int add 0x8000 + byte-perm
static __device__ __forceinline__ u32 pack_rn(float lo, float hi) {
    union { float f; u32 u; } a, b;
    a.f = lo; b.f = hi;
    return __builtin_amdgcn_perm(b.u + 0x8000u, a.u + 0x8000u, 0x07060302u);
}

// ---------------- W prep: fragment-major Wt --------------------------------------
__global__ __launch_bounds__(256) void prep_w(
    const float* __restrict__ wk, const float* __restrict__ wq, const float* __restrict__ wv,
    u16* __restrict__ wt) {
    const int nt = blockIdx.x;   // 0..11
    const int t = threadIdx.x;
#pragma unroll
    for (int ss = 0; ss < 2; ++ss) {
        int slot = t + ss * 256;          // 0..511
        int kc = slot >> 6, lane = slot & 63;
        int ln15 = lane & 15, lq = lane >> 4;
        int cg = nt * 16 + ln15;
        int mat = cg >> 6, col = cg & 63;
        const float* W = (mat == 0) ? wq : (mat == 1) ? wk : wv;
        const float s = (mat == 0) ? 0.0625f * 1.44269504088896f : 1.0f;
        u32 w4[4];
#pragma unroll
        for (int p = 0; p < 2; ++p) {
#pragma unroll
            for (int d = 0; d < 2; ++d) {
                int e0 = kc * 32 + lq * 8 + p * 4 + d * 2;
                u16 lo = f2bf(W[(e0 + 0) * HD + col] * s);
                u16 hi = f2bf(W[(e0 + 1) * HD + col] * s);
                w4[p * 2 + d] = (u32)lo | ((u32)hi << 16);
            }
        }
        u32* dst = (u32*)wt + ((size_t)(nt * 8 + kc) * 64 + lane) * 4;
        *(uint4*)dst = make_uint4(w4[0], w4[1], w4[2], w4[3]);
    }
}

// ---------------- projection GEMM: [16384,256]@[256,192] bf16 MFMA ----------------
__global__ __launch_bounds__(256) void proj_mfma(
    const float* __restrict__ emb, const u16* __restrict__ wt,
    u16* __restrict__ qb, u16* __restrict__ kb, u16* __restrict__ vbt) {
    __shared__ u16 a_s[16 * PADA];
    const int t = threadIdx.x;
    const int lane = t & 63;
    const int wave = t >> 6;
    const int ln15 = lane & 15;
    const int lq = lane >> 4;
    const size_t row0 = (size_t)blockIdx.x * 16;

#pragma unroll
    for (int c = 0; c < 4; ++c) {
        int f = t + c * 256;
        int row = f >> 6, e4 = (f & 63) * 4;
        float4 v = *(const float4*)(emb + (row0 + row) * EMB + e4);
        ushort4 o;
        o.x = f2bf(v.x); o.y = f2bf(v.y); o.z = f2bf(v.z); o.w = f2bf(v.w);
        *(ushort4*)&a_s[row * PADA + e4] = o;
    }
    __syncthreads();

    floatx4 acc[3];
#pragma unroll
    for (int j = 0; j < 3; ++j) {
        floatx4 z = { 0.f, 0.f, 0.f, 0.f };
        acc[j] = z;
    }

#pragma unroll
    for (int kc = 0; kc < 8; ++kc) {
        short8v a = *(const short8v*)&a_s[ln15 * PADA + kc * 32 + lq * 8];
#pragma unroll
        for (int j = 0; j < 3; ++j) {
            short8v b = *(const short8v*)(wt + (((size_t)(wave * 3 + j) * 8 + kc) * 64 + lane) * 8);
            acc[j] = __builtin_amdgcn_mfma_f32_16x16x32_bf16(a, b, acc[j], 0, 0, 0);
        }
    }

#pragma unroll
    for (int j = 0; j < 3; ++j) {
        int cg = (wave * 3 + j) * 16 + ln15;
        int mat = cg >> 6, col = cg & 63;
        if (mat < 2) {
            u16* O = (mat == 0) ? qb : kb;
#pragma unroll
            for (int r = 0; r < 4; ++r)
                O[(row0 + lq * 4 + r) * HD + col] = f2bf(acc[j][r]);
        } else {
            ushort4 o4;
            o4.x = f2bf(acc[j][0]); o4.y = f2bf(acc[j][1]);
            o4.z = f2bf(acc[j][2]); o4.w = f2bf(acc[j][3]);
            size_t bidx = row0 >> 12;
            size_t sl = (row0 & 4095) + lq * 4;
            *(ushort4*)&vbt[(bidx * 64 + col) * SEQ + sl] = o4;
        }
    }
}

// ---------------- flash attention, split-K x4, zero-LDS K-loop ---------------------
// part = b*256 + qt*4 + split; wave w owns keys [kv0+16w, kv0+16w+16) per tile.
// S^T = K.Q^T (16x16x32); P = exp2(S^T) packed in regs; O^T += V^T.P (16x16x16).
__global__ __launch_bounds__(256) void attn_kernel(
    const u16* __restrict__ qb, const u16* __restrict__ kb, const u16* __restrict__ vbt,
    float* __restrict__ po, float* __restrict__ pml) {
    __shared__ u16 q_s[64 * PADQ];    // 8.7 KB
    __shared__ float ored[64 * 66];   // 16.9 KB
    __shared__ float lred[4 * 64];

    const int t = threadIdx.x;
    const int lane = t & 63;
    const int wave = t >> 6;
    const int ln15 = lane & 15;
    const int lq = lane >> 4;

    const int part = blockIdx.x;
    const int b = part >> 8;
    const int qt = (part >> 2) & 63;
    const int split = part & 3;
    const int q0 = qt * 64;

    const u16* __restrict__ qpb = qb + ((size_t)b * SEQ + q0) * HD;
    const u16* __restrict__ kpb = kb + (size_t)b * SEQ * HD;
    const u16* __restrict__ vpb = vbt + (size_t)b * HD * SEQ;

    // stage Q tile to LDS
#pragma unroll
    for (int c = 0; c < 4; ++c) {
        int f = t + c * 256;
        int row = f >> 4, h4 = (f & 15) * 4;
        *(ushort4*)&q_s[row * PADQ + h4] = *(const ushort4*)(qpb + (size_t)row * HD + h4);
    }
    __syncthreads();

    floatx4 oacc[4][4];
#pragma unroll
    for (int ht = 0; ht < 4; ++ht)
#pragma unroll
        for (int nt = 0; nt < 4; ++nt) {
            floatx4 z = { 0.f, 0.f, 0.f, 0.f };
            oacc[ht][nt] = z;
        }
    float lacc[4] = { 0.f, 0.f, 0.f, 0.f };

    // preload tile 0's K/V frags
    int kw = split * 16 * 64 + wave * 16;
    short8v kf0 = *(const short8v*)(kpb + (size_t)(kw + ln15) * HD + lq * 8);
    short8v kf1 = *(const short8v*)(kpb + (size_t)(kw + ln15) * HD + 32 + lq * 8);
    short4v vf[4];
#pragma unroll
    for (int ht = 0; ht < 4; ++ht)
        vf[ht] = *(const short4v*)(vpb + (size_t)(ht * 16 + ln15) * SEQ + kw + lq * 4);

    for (int tt = 0; tt < 16; ++tt) {
        // prefetch next tile (last iter over-reads into adjacent ws - safe)
        const int kwn = kw + 64;
        short8v nk0 = *(const short8v*)(kpb + (size_t)(kwn + ln15) * HD + lq * 8);
        short8v nk1 = *(const short8v*)(kpb + (size_t)(kwn + ln15) * HD + 32 + lq * 8);
        short4v nv[4];
#pragma unroll
        for (int ht = 0; ht < 4; ++ht)
            nv[ht] = *(const short4v*)(vpb + (size_t)(ht * 16 + ln15) * SEQ + kwn + lq * 4);

        // S^T tiles: D[m=key][n=qrow]; Q B-frags from LDS
        floatx4 s[4];
#pragma unroll
        for (int nt = 0; nt < 4; ++nt) {
            short8v q0f = *(const short8v*)&q_s[(nt * 16 + ln15) * PADQ + lq * 8];
            short8v q1f = *(const short8v*)&q_s[(nt * 16 + ln15) * PADQ + 32 + lq * 8];
            floatx4 z = { 0.f, 0.f, 0.f, 0.f };
            s[nt] = __builtin_amdgcn_mfma_f32_16x16x32_bf16(kf0, q0f, z, 0, 0, 0);
            s[nt] = __builtin_amdgcn_mfma_f32_16x16x32_bf16(kf1, q1f, s[nt], 0, 0, 0);
        }

        // P = exp2(S^T), packed to bf16 in regs (C-layout == 16x16x16 B-layout)
        short4v pf[4];
#pragma unroll
        for (int nt = 0; nt < 4; ++nt) {
            float p0 = __builtin_amdgcn_exp2f(s[nt][0]);
            float p1 = __builtin_amdgcn_exp2f(s[nt][1]);
            float p2 = __builtin_amdgcn_exp2f(s[nt][2]);
            float p3 = __builtin_amdgcn_exp2f(s[nt][3]);
            lacc[nt] += (p0 + p1) + (p2 + p3);
            union { u32 u[2]; short4v s4; } pk;
            pk.u[0] = pack_rn(p0, p1);
            pk.u[1] = pack_rn(p2, p3);
            pf[nt] = pk.s4;
        }

        // O^T += V^T . P
#pragma unroll
        for (int ht = 0; ht < 4; ++ht)
#pragma unroll
            for (int nt = 0; nt < 4; ++nt)
                oacc[ht][nt] = __builtin_amdgcn_mfma_f32_16x16x16bf16_1k(
                    vf[ht], pf[nt], oacc[ht][nt], 0, 0, 0);

        kw = kwn;
        kf0 = nk0; kf1 = nk1;
#pragma unroll
        for (int ht = 0; ht < 4; ++ht) vf[ht] = nv[ht];
    }

    // ---- epilogue: cross-wave reduce ----
#pragma unroll
    for (int nt = 0; nt < 4; ++nt) {
        lacc[nt] += __shfl_xor(lacc[nt], 16);
        lacc[nt] += __shfl_xor(lacc[nt], 32);
    }
    if (lq == 0) {
#pragma unroll
        for (int nt = 0; nt < 4; ++nt)
            lred[wave * 64 + nt * 16 + ln15] = lacc[nt];
    }

    for (int s4 = 0; s4 < 4; ++s4) {
        if (wave == s4) {
#pragma unroll
            for (int ht = 0; ht < 4; ++ht)
#pragma unroll
                for (int nt = 0; nt < 4; ++nt)
#pragma unroll
                    for (int r = 0; r < 4; ++r) {
                        int idx = (ht * 16 + lq * 4 + r) * 66 + nt * 16 + ln15;
                        if (s4 == 0) ored[idx] = oacc[ht][nt][r];
                        else ored[idx] += oacc[ht][nt][r];
                    }
        }
        __syncthreads();
    }

    float* __restrict__ pob = po + (size_t)part * 4096;
#pragma unroll
    for (int i = 0; i < 16; ++i) {
        int f = t + i * 256;
        pob[f] = ored[(f >> 6) * 66 + (f & 63)];
    }
    if (t < 64)
        pml[part * 64 + t] = lred[t] + lred[64 + t] + lred[128 + t] + lred[192 + t];
}

// ---------------- split reduction: 1024 blocks, 16 q-rows each ---------------------
__global__ __launch_bounds__(256) void reduce_kernel(
    const float* __restrict__ po, const float* __restrict__ pml,
    float* __restrict__ out) {
    __shared__ float os[16 * 65];
    __shared__ float ls[16];
    const int t = threadIdx.x;
    const int bq = blockIdx.x >> 2;       // b*64 + qtile
    const int sub = blockIdx.x & 3;
    const int part0 = bq * 4;
    const int q0l = sub * 16;

#pragma unroll
    for (int i = 0; i < 4; ++i) {
        int f = t + i * 256;              // 0..1023: h = f>>4, q = f&15
        int h = f >> 4, q = f & 15;
        size_t base = (size_t)part0 * 4096 + h * 64 + q0l + q;
        float a = po[base] + po[base + 4096] + po[base + 8192] + po[base + 12288];
        os[q * 65 + h] = a;
    }
    if (t < 16)
        ls[t] = pml[part0 * 64 + q0l + t] + pml[(part0 + 1) * 64 + q0l + t]
              + pml[(part0 + 2) * 64 + q0l + t] + pml[(part0 + 3) * 64 + q0l + t];
    __syncthreads();

    const int q = t >> 4, h4 = (t & 15) * 4;
    const float inv = 1.0f / ls[q];
    float4 r;
    r.x = os[q * 65 + h4 + 0] * inv;
    r.y = os[q * 65 + h4 + 1] * inv;
    r.z = os[q * 65 + h4 + 2] * inv;
    r.w = os[q * 65 + h4 + 3] * inv;
    size_t orow = (size_t)(bq >> 6) * SEQ + (size_t)(bq & 63) * 64 + q0l + q;
    *(float4*)&out[orow * HD + h4] = r;
}

extern "C" void kernel_launch(void* const* d_in, const int* in_sizes, int n_in,
                              void* d_out, int out_size, void* d_ws, size_t ws_size,
                              hipStream_t stream) {
    const float* emb = (const float*)d_in[0];
    const float* wk  = (const float*)d_in[1];
    const float* wq  = (const float*)d_in[2];
    const float* wv  = (const float*)d_in[3];

    // ws: qb 2M @0, kb 2M @2M, vbt 2M @4M, wt 96K @6M, po 16M @6.25M, pml 256K @22.25M
    u16* qb  = (u16*)d_ws;
    u16* kb  = (u16*)((char*)d_ws + (size_t)2 * 1024 * 1024);
    u16* vbt = (u16*)((char*)d_ws + (size_t)4 * 1024 * 1024);
    u16* wt  = (u16*)((char*)d_ws + (size_t)6 * 1024 * 1024);
    float* po  = (float*)((char*)d_ws + (size_t)6 * 1024 * 1024 + 256 * 1024);
    float* pml = (float*)((char*)d_ws + (size_t)22 * 1024 * 1024 + 256 * 1024);
    float* out = (float*)d_out;

    prep_w<<<12, 256, 0, stream>>>(wk, wq, wv, wt);
    proj_mfma<<<1024, 256, 0, stream>>>(emb, wt, qb, kb, vbt);
    attn_kernel<<<1024, 256, 0, stream>>>(qb, kb, vbt, po, pml);
    reduce_kernel<<<1024, 256, 0, stream>>>(po, pml, out);
}